// Round 16
// baseline (32.906 us; speedup 1.0000x reference)
//
#include <hip/hip_runtime.h>
#include <hip/hip_bf16.h>
#include <math.h>

// MultiVariateAttention: out[b,u] = exp(mvn_logpdf(x[b]; mu[u], diag(s[u])))
// B = U = 4096, D = 16, fp32 in/out.
//
// R16: x through the SCALAR pipe (s_load), zero LDS in the main loop.
// R13/R15 accounting: R11's loop = three ~10us co-floors (store, VALU, LDS).
// Here the LDS floor is removed: each wave owns one b-row per iteration
// (wave-uniform row index via readfirstlane -> s_load_dwordx4; x operand
// feeds v_fma_f32 as the 1 legal SGPR source). 64 lanes x u-pair = 128 u
// per row -> 512B contiguous wave-stores. Params gathered once per block
// via LDS prologue (hw rcp, 2 hw v_log per thread). 18KB LDS -> 4 blocks/CU.

#define TPB 256
#define DD  16
#define UBL 128    // u per block (64 lanes x 2)
#define BBL 128    // b rows per block; grid 32x32 = 1024 blocks = 4/CU
#define NIT (BBL / 4)

typedef float v2f __attribute__((ext_vector_type(2)));

static constexpr float L2E   = 1.4426950408889634f;   // log2(e)
static constexpr float HL2PI = 0.91893853320467274f;  // 0.5*ln(2*pi)

__global__ __launch_bounds__(TPB, 4) void mva_sx(
    const float* __restrict__ x,      // [B,1,D]
    const float* __restrict__ units,  // [U,D]
    const float* __restrict__ attn,   // [U,D,D]
    float* __restrict__ out,          // [B,U]
    int U)
{
    const int tid    = threadIdx.x;
    const int u_base = blockIdx.x * UBL;
    const int b_base = blockIdx.y * BBL;

    __shared__ float  a1L[DD][UBL + 2];
    __shared__ float  a2L[DD][UBL + 2];
    __shared__ float2 bpL[2][UBL];     // {qn, log2-prod} partials per d-half

    // ---- prologue: 128u x 16d params; thread = (ul, half) -> 8 d's ----
    {
        const int ul   = tid & 127;
        const int half = tid >> 7;
        const int d0   = half * 8;
        const int u    = u_base + ul;
        const float* ar = attn + (size_t)u * DD * DD;
        float4 m0 = *reinterpret_cast<const float4*>(units + (size_t)u * DD + d0);
        float4 m1 = *reinterpret_cast<const float4*>(units + (size_t)u * DD + d0 + 4);
        const float mu[8] = {m0.x, m0.y, m0.z, m0.w, m1.x, m1.y, m1.z, m1.w};
        float qn = 0.f, prod = 1.f;
#pragma unroll
        for (int k = 0; k < 8; ++k) {
            const int d = d0 + k;
            float s = fmaxf(ar[d * (DD + 1)], 1e-6f);
            float r = __builtin_amdgcn_rcpf(s);   // v_rcp_f32
            float w = r * r;
            a1L[d][ul] = L2E * mu[k] * w;
            a2L[d][ul] = -0.5f * L2E * w;
            qn   = fmaf(mu[k] * w, mu[k], qn);
            prod *= s;                             // in [0.05^8, 0.3^8]: normal
        }
        bpL[half][ul] = make_float2(qn, __builtin_amdgcn_logf(prod)); // log2
    }
    __syncthreads();

    // ---- per-thread u-pair params ----
    const int up = tid & 63;                       // u = u_base + up*2, +1
    const int wv = __builtin_amdgcn_readfirstlane(tid >> 6);  // wave id 0..3
    v2f a1p[DD], a2p[DD];
#pragma unroll
    for (int d = 0; d < DD; ++d) {
        a1p[d] = *reinterpret_cast<const v2f*>(&a1L[d][up * 2]);
        a2p[d] = *reinterpret_cast<const v2f*>(&a2L[d][up * 2]);
    }
    float bias0, bias1;
    {
        float2 qa = bpL[0][up * 2],     qb = bpL[1][up * 2];
        float2 ra = bpL[0][up * 2 + 1], rb = bpL[1][up * 2 + 1];
        bias0 = fmaf(-0.5f * L2E, qa.x + qb.x, -(qa.y + qb.y) - DD * L2E * HL2PI);
        bias1 = fmaf(-0.5f * L2E, ra.x + rb.x, -(ra.y + rb.y) - DD * L2E * HL2PI);
    }

    // ---- main loop: wave wv owns rows b = it*4 + wv; x via s_load ----
    const float* xw = x + (size_t)(b_base + wv) * DD;   // wave-uniform (SGPR)
    float* ow = out + (size_t)(b_base + wv) * U + u_base + up * 2;

    float4 xa = *reinterpret_cast<const float4*>(xw + 0);
    float4 xb = *reinterpret_cast<const float4*>(xw + 4);
    float4 xc = *reinterpret_cast<const float4*>(xw + 8);
    float4 xd = *reinterpret_cast<const float4*>(xw + 12);

#pragma unroll 2
    for (int it = 0; it < NIT; ++it) {
        const float4 c0 = xa, c1 = xb, c2 = xc, c3 = xd;
        if (it + 1 < NIT) {                         // uniform branch
            const float* xn = xw + (size_t)(it + 1) * 4 * DD;
            xa = *reinterpret_cast<const float4*>(xn + 0);
            xb = *reinterpret_cast<const float4*>(xn + 4);
            xc = *reinterpret_cast<const float4*>(xn + 8);
            xd = *reinterpret_cast<const float4*>(xn + 12);
        }
        float acc0 = bias0, acc1 = bias1;
        float t;
        // x component is an SGPR: v_fma_f32 with 1 scalar operand (legal)
#define STEP(C, DK) \
        t = fmaf(C, a2p[DK][0], a1p[DK][0]); acc0 = fmaf(C, t, acc0); \
        t = fmaf(C, a2p[DK][1], a1p[DK][1]); acc1 = fmaf(C, t, acc1);
        STEP(c0.x, 0)  STEP(c0.y, 1)  STEP(c0.z, 2)  STEP(c0.w, 3)
        STEP(c1.x, 4)  STEP(c1.y, 5)  STEP(c1.z, 6)  STEP(c1.w, 7)
        STEP(c2.x, 8)  STEP(c2.y, 9)  STEP(c2.z, 10) STEP(c2.w, 11)
        STEP(c3.x, 12) STEP(c3.y, 13) STEP(c3.z, 14) STEP(c3.w, 15)
#undef STEP
        float2 o;
        o.x = __builtin_amdgcn_exp2f(acc0);
        o.y = __builtin_amdgcn_exp2f(acc1);
        // 64 lanes x 8B = 512B contiguous; never awaited in-loop
        *reinterpret_cast<float2*>(ow + (size_t)it * 4 * U) = o;
    }
}

extern "C" void kernel_launch(void* const* d_in, const int* in_sizes, int n_in,
                              void* d_out, int out_size, void* d_ws, size_t ws_size,
                              hipStream_t stream) {
    const float* x     = (const float*)d_in[0];  // [B,1,D]
    const float* units = (const float*)d_in[1];  // [U,D]
    const float* attn  = (const float*)d_in[2];  // [U,D,D]
    float* out = (float*)d_out;

    const int B = in_sizes[0] / DD;  // 4096
    const int U = in_sizes[1] / DD;  // 4096

    dim3 grid(U / UBL, B / BBL);     // (32, 32) = 1024 blocks
    mva_sx<<<grid, TPB, 0, stream>>>(x, units, attn, out, U);
}

// Round 17
// 22.224 us; speedup vs baseline: 1.4807x; 1.4807x over previous
//
#include <hip/hip_runtime.h>
#include <hip/hip_bf16.h>
#include <math.h>

// MultiVariateAttention: out[b,u] = exp(mvn_logpdf(x[b]; mu[u], diag(s[u])))
// B = U = 4096, D = 16, fp32 in/out.
//
// R17 = R11 (22.5us best) + ONE unconfounded lever: halve the LDS-read
// pipe (the third ~10us co-floor from R13's accounting).
//  - u-quad per thread: each ds_read_b128 (4 x-values) now feeds 4 u's
//    (32 FMA-ops) instead of 2 -> wave-level LDS reads per CU halved.
//  - xs row stride XST=20 floats: 8 rows/wave start at banks
//    {0,20,8,28,16,4,24,12} -> float4 spans partition all 32 banks;
//    8-lane groups share an address (broadcast). Conflict-free.
//  - occupancy kept in R11's regime (no launch_bounds min; ~3 blocks/CU);
//    grid (128,16) = 2048 blocks. Store fragments 128B/row (proven
//    non-binding in R7/R14). Everything else = R11 verbatim.

#define TPB 256
#define DD  16
#define UB  32     // u's per block
#define BB  256    // b's per block
#define XST 20     // xs row stride (floats): conflict-free, 16B-aligned

typedef float v2f __attribute__((ext_vector_type(2)));

static constexpr float L2E   = 1.4426950408889634f;   // log2(e)
static constexpr float HL2PI = 0.91893853320467274f;  // 0.5*ln(2*pi)

__global__ __launch_bounds__(TPB) void mva_tile(
    const float* __restrict__ x,      // [B,1,D]
    const float* __restrict__ units,  // [U,D]
    const float* __restrict__ attn,   // [U,D,D]
    float* __restrict__ out,          // [B,U]
    int U)
{
    const int tid    = threadIdx.x;
    const int u_base = blockIdx.x * UB;
    const int b_base = blockIdx.y * BB;

    __shared__ __align__(16) float xs[BB][XST];     // 20 KB
    __shared__ __align__(16) float a1L[DD][UB + 4]; // stride 36: float4-aligned
    __shared__ __align__(16) float a2L[DD][UB + 4];
    __shared__ __align__(16) float biasL[UB];

    // ---- stage x tile: coalesced float4 loads -> padded rows ----
    const float* xb = x + (size_t)b_base * DD;
#pragma unroll
    for (int r = 0; r < (BB * DD) / (TPB * 4); ++r) {  // 4 iters
        const int q   = (r * TPB + tid) * 4;
        const int row = q >> 4, col = q & 15;
        *reinterpret_cast<float4*>(&xs[row][col]) =
            *reinterpret_cast<const float4*>(xb + q);
    }

    // ---- param gather: 512 (u,d)-pairs over 256 threads (R11 verbatim) ----
    {
        const int ul = tid >> 3;          // 0..31  local u
        const int d0 = (tid & 7) * 2;     // 0,2,..,14
        const int u  = u_base + ul;
        float2 m = *reinterpret_cast<const float2*>(units + (size_t)u * DD + d0);
        const float* ar = attn + (size_t)u * DD * DD;
        float s0 = fmaxf(ar[d0 * (DD + 1)], 1e-6f);
        float s1 = fmaxf(ar[(d0 + 1) * (DD + 1)], 1e-6f);
        float w0 = 1.f / (s0 * s0);
        float w1 = 1.f / (s1 * s1);
        a1L[d0][ul]     = L2E * m.x * w0;
        a2L[d0][ul]     = -0.5f * L2E * w0;
        a1L[d0 + 1][ul] = L2E * m.y * w1;
        a2L[d0 + 1][ul] = -0.5f * L2E * w1;
        float bn = -0.5f * (m.x * m.x * w0 + m.y * m.y * w1)
                 - (logf(s0) + logf(s1));
        bn += __shfl_xor(bn, 1, 8);
        bn += __shfl_xor(bn, 2, 8);
        bn += __shfl_xor(bn, 4, 8);
        if ((tid & 7) == 0) biasL[ul] = L2E * (bn - DD * HL2PI);
    }
    __syncthreads();

    // ---- per-thread u-quad params (float4-aligned LDS reads) ----
    const int uq = tid & 7;               // u = u_base + uq*4 .. +3
    const int br = tid >> 3;              // 32 concurrent b-rows
    v2f a1A[DD], a1B[DD], a2A[DD], a2B[DD];
#pragma unroll
    for (int d = 0; d < DD; ++d) {
        float4 q1 = *reinterpret_cast<const float4*>(&a1L[d][uq * 4]);
        a1A[d] = (v2f){q1.x, q1.y};  a1B[d] = (v2f){q1.z, q1.w};
        float4 q2 = *reinterpret_cast<const float4*>(&a2L[d][uq * 4]);
        a2A[d] = (v2f){q2.x, q2.y};  a2B[d] = (v2f){q2.z, q2.w};
    }
    float4 bq = *reinterpret_cast<const float4*>(&biasL[uq * 4]);
    const v2f biasA = (v2f){bq.x, bq.y}, biasB = (v2f){bq.z, bq.w};

    // ---- main loop: 8 iters x 32 rows; 4 ds_read feed 64 pk_fma ----
    float* orow = out + (size_t)b_base * U + u_base + uq * 4;
#pragma unroll 2
    for (int it = 0; it < BB / 32; ++it) {
        const int b = it * 32 + br;
        float4 xv0 = *reinterpret_cast<const float4*>(&xs[b][0]);
        float4 xv1 = *reinterpret_cast<const float4*>(&xs[b][4]);
        float4 xv2 = *reinterpret_cast<const float4*>(&xs[b][8]);
        float4 xv3 = *reinterpret_cast<const float4*>(&xs[b][12]);
        v2f accA = biasA, accB = biasB;
        v2f xx, t;
#define STEP(C, DK) \
        xx = (v2f){C, C}; \
        t = __builtin_elementwise_fma(xx, a2A[DK], a1A[DK]); \
        accA = __builtin_elementwise_fma(xx, t, accA); \
        t = __builtin_elementwise_fma(xx, a2B[DK], a1B[DK]); \
        accB = __builtin_elementwise_fma(xx, t, accB);
        STEP(xv0.x, 0)  STEP(xv0.y, 1)  STEP(xv0.z, 2)  STEP(xv0.w, 3)
        STEP(xv1.x, 4)  STEP(xv1.y, 5)  STEP(xv1.z, 6)  STEP(xv1.w, 7)
        STEP(xv2.x, 8)  STEP(xv2.y, 9)  STEP(xv2.z, 10) STEP(xv2.w, 11)
        STEP(xv3.x, 12) STEP(xv3.y, 13) STEP(xv3.z, 14) STEP(xv3.w, 15)
#undef STEP
        float4 o;
        o.x = __builtin_amdgcn_exp2f(accA[0]);
        o.y = __builtin_amdgcn_exp2f(accA[1]);
        o.z = __builtin_amdgcn_exp2f(accB[0]);
        o.w = __builtin_amdgcn_exp2f(accB[1]);
        // 8 threads x 16B = 128B per row; stores stream un-awaited
        *reinterpret_cast<float4*>(orow + (size_t)b * U) = o;
    }
}

extern "C" void kernel_launch(void* const* d_in, const int* in_sizes, int n_in,
                              void* d_out, int out_size, void* d_ws, size_t ws_size,
                              hipStream_t stream) {
    const float* x     = (const float*)d_in[0];  // [B,1,D]
    const float* units = (const float*)d_in[1];  // [U,D]
    const float* attn  = (const float*)d_in[2];  // [U,D,D]
    float* out = (float*)d_out;

    const int B = in_sizes[0] / DD;  // 4096
    const int U = in_sizes[1] / DD;  // 4096

    dim3 grid(U / UB, B / BB);       // (128, 16) = 2048 blocks
    mva_tile<<<grid, TPB, 0, stream>>>(x, units, attn, out, U);
}

// Round 19
// 21.728 us; speedup vs baseline: 1.5144x; 1.0228x over previous
//
#include <hip/hip_runtime.h>
#include <hip/hip_bf16.h>
#include <math.h>

// MultiVariateAttention: out[b,u] = exp(mvn_logpdf(x[b]; mu[u], diag(s[u])))
// B = U = 4096, D = 16, fp32 in/out.
//
// R19 = R18 with the compile fix: __builtin_nontemporal_store requires a
// clang ext_vector_type, not HIP's float4 struct. v4f alias used for the
// output store. Hypothesis unchanged: the 64MB output stream churns the
// 32MB aggregate L2 (allocate+evict per line); nt stores stream past L2,
// lifting in-loop write BW from the measured 4.2 TB/s toward 6 TB/s.
// Everything else = R17 verbatim.

#define TPB 256
#define DD  16
#define UB  32     // u's per block
#define BB  256    // b's per block
#define XST 20     // xs row stride (floats): conflict-free, 16B-aligned

typedef float v2f __attribute__((ext_vector_type(2)));
typedef float v4f __attribute__((ext_vector_type(4)));

static constexpr float L2E   = 1.4426950408889634f;   // log2(e)
static constexpr float HL2PI = 0.91893853320467274f;  // 0.5*ln(2*pi)

__global__ __launch_bounds__(TPB) void mva_tile(
    const float* __restrict__ x,      // [B,1,D]
    const float* __restrict__ units,  // [U,D]
    const float* __restrict__ attn,   // [U,D,D]
    float* __restrict__ out,          // [B,U]
    int U)
{
    const int tid    = threadIdx.x;
    const int u_base = blockIdx.x * UB;
    const int b_base = blockIdx.y * BB;

    __shared__ __align__(16) float xs[BB][XST];     // 20 KB
    __shared__ __align__(16) float a1L[DD][UB + 4]; // stride 36: float4-aligned
    __shared__ __align__(16) float a2L[DD][UB + 4];
    __shared__ __align__(16) float biasL[UB];

    // ---- stage x tile: coalesced float4 loads -> padded rows ----
    const float* xb = x + (size_t)b_base * DD;
#pragma unroll
    for (int r = 0; r < (BB * DD) / (TPB * 4); ++r) {  // 4 iters
        const int q   = (r * TPB + tid) * 4;
        const int row = q >> 4, col = q & 15;
        *reinterpret_cast<float4*>(&xs[row][col]) =
            *reinterpret_cast<const float4*>(xb + q);
    }

    // ---- param gather: 512 (u,d)-pairs over 256 threads ----
    {
        const int ul = tid >> 3;          // 0..31  local u
        const int d0 = (tid & 7) * 2;     // 0,2,..,14
        const int u  = u_base + ul;
        float2 m = *reinterpret_cast<const float2*>(units + (size_t)u * DD + d0);
        const float* ar = attn + (size_t)u * DD * DD;
        float s0 = fmaxf(ar[d0 * (DD + 1)], 1e-6f);
        float s1 = fmaxf(ar[(d0 + 1) * (DD + 1)], 1e-6f);
        float w0 = 1.f / (s0 * s0);
        float w1 = 1.f / (s1 * s1);
        a1L[d0][ul]     = L2E * m.x * w0;
        a2L[d0][ul]     = -0.5f * L2E * w0;
        a1L[d0 + 1][ul] = L2E * m.y * w1;
        a2L[d0 + 1][ul] = -0.5f * L2E * w1;
        float bn = -0.5f * (m.x * m.x * w0 + m.y * m.y * w1)
                 - (logf(s0) + logf(s1));
        bn += __shfl_xor(bn, 1, 8);
        bn += __shfl_xor(bn, 2, 8);
        bn += __shfl_xor(bn, 4, 8);
        if ((tid & 7) == 0) biasL[ul] = L2E * (bn - DD * HL2PI);
    }
    __syncthreads();

    // ---- per-thread u-quad params (float4-aligned LDS reads) ----
    const int uq = tid & 7;               // u = u_base + uq*4 .. +3
    const int br = tid >> 3;              // 32 concurrent b-rows
    v2f a1A[DD], a1B[DD], a2A[DD], a2B[DD];
#pragma unroll
    for (int d = 0; d < DD; ++d) {
        float4 q1 = *reinterpret_cast<const float4*>(&a1L[d][uq * 4]);
        a1A[d] = (v2f){q1.x, q1.y};  a1B[d] = (v2f){q1.z, q1.w};
        float4 q2 = *reinterpret_cast<const float4*>(&a2L[d][uq * 4]);
        a2A[d] = (v2f){q2.x, q2.y};  a2B[d] = (v2f){q2.z, q2.w};
    }
    float4 bq = *reinterpret_cast<const float4*>(&biasL[uq * 4]);
    const v2f biasA = (v2f){bq.x, bq.y}, biasB = (v2f){bq.z, bq.w};

    // ---- main loop: 8 iters x 32 rows; 4 ds_read feed 64 pk_fma ----
    float* orow = out + (size_t)b_base * U + u_base + uq * 4;
#pragma unroll 2
    for (int it = 0; it < BB / 32; ++it) {
        const int b = it * 32 + br;
        float4 xv0 = *reinterpret_cast<const float4*>(&xs[b][0]);
        float4 xv1 = *reinterpret_cast<const float4*>(&xs[b][4]);
        float4 xv2 = *reinterpret_cast<const float4*>(&xs[b][8]);
        float4 xv3 = *reinterpret_cast<const float4*>(&xs[b][12]);
        v2f accA = biasA, accB = biasB;
        v2f xx, t;
#define STEP(C, DK) \
        xx = (v2f){C, C}; \
        t = __builtin_elementwise_fma(xx, a2A[DK], a1A[DK]); \
        accA = __builtin_elementwise_fma(xx, t, accA); \
        t = __builtin_elementwise_fma(xx, a2B[DK], a1B[DK]); \
        accB = __builtin_elementwise_fma(xx, t, accB);
        STEP(xv0.x, 0)  STEP(xv0.y, 1)  STEP(xv0.z, 2)  STEP(xv0.w, 3)
        STEP(xv1.x, 4)  STEP(xv1.y, 5)  STEP(xv1.z, 6)  STEP(xv1.w, 7)
        STEP(xv2.x, 8)  STEP(xv2.y, 9)  STEP(xv2.z, 10) STEP(xv2.w, 11)
        STEP(xv3.x, 12) STEP(xv3.y, 13) STEP(xv3.z, 14) STEP(xv3.w, 15)
#undef STEP
        v4f o;
        o.x = __builtin_amdgcn_exp2f(accA[0]);
        o.y = __builtin_amdgcn_exp2f(accA[1]);
        o.z = __builtin_amdgcn_exp2f(accB[0]);
        o.w = __builtin_amdgcn_exp2f(accB[1]);
        // Non-temporal: stream past L2 (no allocate/evict churn).
        __builtin_nontemporal_store(o,
            reinterpret_cast<v4f*>(orow + (size_t)b * U));
    }
}

extern "C" void kernel_launch(void* const* d_in, const int* in_sizes, int n_in,
                              void* d_out, int out_size, void* d_ws, size_t ws_size,
                              hipStream_t stream) {
    const float* x     = (const float*)d_in[0];  // [B,1,D]
    const float* units = (const float*)d_in[1];  // [U,D]
    const float* attn  = (const float*)d_in[2];  // [U,D,D]
    float* out = (float*)d_out;

    const int B = in_sizes[0] / DD;  // 4096
    const int U = in_sizes[1] / DD;  // 4096

    dim3 grid(U / UB, B / BB);       // (128, 16) = 2048 blocks
    mva_tile<<<grid, TPB, 0, stream>>>(x, units, attn, out, U);
}